// Round 1
// baseline (152.234 us; speedup 1.0000x reference)
//
#include <hip/hip_runtime.h>
#include <hip/hip_bf16.h>

// KAN layer: out = einsum('bik,jik->bj', rbf(x), W) + silu(x)@Wb^T, then LN.
// GEMM view: C[4096,512] = A[4096,8704] * B[512,8704]^T in bf16 MFMA.
//
// d_ws layout (113,770,496 B total):
//   A  bf16 [4096][8704]     @ 0          (71,303,168 B)  A = [basis | silu(x)]
//   Bm bf16 [512][8704]      @ 71303168   ( 8,912,896 B)  Bm = [W | Wb]
//   Cp bf16 [8][4096][512]   @ 80216064   (33,554,432 B)  split-K partials (bf16)

typedef __bf16 bf16x8 __attribute__((ext_vector_type(8)));
typedef __bf16 bf16x4 __attribute__((ext_vector_type(4)));
typedef float  f32x4  __attribute__((ext_vector_type(4)));

#define KT 8704            // total K = 512*16 + 512
#define SPLITS 8
#define KS (KT / SPLITS)   // 1088 = 34 iters of BK=32
#define NIT (KS / 32)
#define CPE (4096 * 512)   // elements per partial
#define LBUF (128 * 32)    // one LDS tile buffer, elements

__device__ __forceinline__ void gll16(const __bf16* g, __bf16* l) {
    __builtin_amdgcn_global_load_lds(
        (const __attribute__((address_space(1))) void*)g,
        (__attribute__((address_space(3))) void*)l, 16, 0, 0);
}

// ---- kernel 1: A = [rbf basis | silu(x)], Bm = [W | Wb], both bf16 --------
// centers linspace(-2,2,16), h = 4/15 => z_k = 3.75x + 7.5 - k
__global__ void prep_AB(const float* __restrict__ x, const float* __restrict__ W,
                        const float* __restrict__ Wb, __bf16* __restrict__ A,
                        __bf16* __restrict__ B) {
    if (blockIdx.x < 8192) {                     // A-part: 1 thread per x elem
        int t = blockIdx.x * 256 + threadIdx.x;  // 0 .. 4096*512
        int b = t >> 9;
        int i = t & 511;
        float xv = x[t];
        float zb = 3.75f * xv + 7.5f;
        bf16x8 lo, hi;
#pragma unroll
        for (int k = 0; k < 8; ++k) { float z = zb - (float)k; lo[k]   = (__bf16)__expf(-z * z); }
#pragma unroll
        for (int k = 8; k < 16; ++k){ float z = zb - (float)k; hi[k-8] = (__bf16)__expf(-z * z); }
        size_t base = (size_t)b * KT + (size_t)i * 16;
        *(bf16x8*)(A + base)     = lo;
        *(bf16x8*)(A + base + 8) = hi;
        float s = xv / (1.0f + __expf(-xv));     // silu
        A[(size_t)b * KT + 8192 + i] = (__bf16)s;
    } else {                                     // B-part: cast W|Wb, 4 elems/thread
        int t = (blockIdx.x - 8192) * 256 + threadIdx.x;  // 0 .. 512*2176
        int j = t / 2176;
        int c = (t - j * 2176) * 4;
        float4 v;
        if (c < 8192) v = *(const float4*)&W[(size_t)j * 8192 + c];
        else          v = *(const float4*)&Wb[(size_t)j * 512 + (c - 8192)];
        bf16x4 o;
        o[0] = (__bf16)v.x; o[1] = (__bf16)v.y; o[2] = (__bf16)v.z; o[3] = (__bf16)v.w;
        *(bf16x4*)&B[(size_t)j * KT + c] = o;
    }
}

// ---- kernel 2: split-K GEMM, 128x128, BK=32 -------------------------------
// R0 post-mortem: the 2-buffer loop's __syncthreads() compiles to
// `s_waitcnt vmcnt(0); s_barrier` — it drains the tile-(it+1) DMA issued only
// ~300 cyc earlier against ~500-900 cyc L2/LLC latency. MfmaUtil 25.7%,
// VALUBusy 13.5%, HBM 24%, bank-conflict 0 => pure barrier-drain stall.
// Fix (T4): depth-2 prefetch into 3 LDS buffers, raw s_barrier, and a COUNTED
// `s_waitcnt vmcnt(4)` — wait only for the older in-flight tile; the newest
// tile's 4 loads stay in flight ACROSS the barrier and get a full iteration
// to land. Tail prefetch reads <=112 B past A/B but stays inside mapped ws
// (lands in the next ws region); the garbage goes to an unused buffer.
// LDS 48 KB => 3 blocks/CU (was 4) — pipeline replaces the lost TLP.
__global__ __launch_bounds__(256, 3) void gemm_bt(const __bf16* __restrict__ A,
                                                  const __bf16* __restrict__ B,
                                                  __bf16* __restrict__ Cp) {
    __shared__ __attribute__((aligned(16))) __bf16 As[3 * LBUF];
    __shared__ __attribute__((aligned(16))) __bf16 Bs[3 * LBUF];

    const int tid  = threadIdx.x;
    const int wave = tid >> 6, lane = tid & 63;
    const int q    = lane >> 4, r16 = lane & 15;
    const int m0 = blockIdx.x * 128, n0 = blockIdx.y * 128, k0 = blockIdx.z * KS;
    const int wm = wave & 1, wn = wave >> 1;

    // staging source (swizzled): chunk c holds global (row=c>>2, qk=(c&3)^((row>>1)&3))
    const int row0 = tid >> 2, qk0 = (tid & 3) ^ ((row0 >> 1) & 3);
    const int row1 = row0 + 64, qk1 = (tid & 3) ^ ((row1 >> 1) & 3);
    const __bf16* gA0 = A + (size_t)(m0 + row0) * KT + k0 + qk0 * 8;
    const __bf16* gA1 = A + (size_t)(m0 + row1) * KT + k0 + qk1 * 8;
    const __bf16* gB0 = B + (size_t)(n0 + row0) * KT + k0 + qk0 * 8;
    const __bf16* gB1 = B + (size_t)(n0 + row1) * KT + k0 + qk1 * 8;

    f32x4 acc[4][4] = {};

    const int qa = q ^ ((r16 >> 1) & 3);         // de-swizzle for reads
    const int awOff = (wm * 64 + r16) * 32 + qa * 8;
    const int bwOff = (wn * 64 + r16) * 32 + qa * 8;

    // stage tile t into LDS buffer sb (4 gll16 per thread => 4 vmcnt slots/wave)
    auto stage = [&](int t, int sb) {
        const int ko = t * 32;
        const int so = sb * LBUF;
        gll16(gA0 + ko, &As[so + tid * 8]);
        gll16(gA1 + ko, &As[so + (tid + 256) * 8]);
        gll16(gB0 + ko, &Bs[so + tid * 8]);
        gll16(gB1 + ko, &Bs[so + (tid + 256) * 8]);
    };

    auto compute = [&](int cb) {
        const __bf16* Aw = &As[cb * LBUF + awOff];
        const __bf16* Bw = &Bs[cb * LBUF + bwOff];
        bf16x8 af[4], bg[4];
#pragma unroll
        for (int mi = 0; mi < 4; ++mi) af[mi] = *(const bf16x8*)(Aw + mi * 512);
#pragma unroll
        for (int ni = 0; ni < 4; ++ni) bg[ni] = *(const bf16x8*)(Bw + ni * 512);
        __builtin_amdgcn_s_setprio(1);           // T5: MFMA cluster priority
#pragma unroll
        for (int mi = 0; mi < 4; ++mi)
#pragma unroll
            for (int ni = 0; ni < 4; ++ni)
                acc[mi][ni] = __builtin_amdgcn_mfma_f32_16x16x32_bf16(
                    af[mi], bg[ni], acc[mi][ni], 0, 0, 0);
        __builtin_amdgcn_s_setprio(0);
    };

    // prologue: tiles 0,1 in flight (8 loads); wait for tile 0 only.
    stage(0, 0);
    stage(1, 1);
    asm volatile("s_waitcnt vmcnt(4)" ::: "memory");
    __builtin_amdgcn_s_barrier();

    int cb = 0;                                  // compute buffer = it % 3
    for (int it = 0; it < NIT - 1; ++it) {
        int sb = cb - 1; if (sb < 0) sb = 2;     // (it+2) % 3 — buffer freed at it-1
        stage(it + 2, sb);                       // issue-only; never waited to 0
        compute(cb);
        // counted wait: of the 8 outstanding loads, require the oldest 4
        // (tile it+1) done; tile it+2's 4 remain in flight across the barrier.
        asm volatile("s_waitcnt vmcnt(4)" ::: "memory");
        __builtin_amdgcn_s_barrier();
        cb = (cb == 2) ? 0 : cb + 1;
    }
    compute(cb);                                 // last tile: already waited

    // epilogue: C/D layout col=lane&15, row=(lane>>4)*4+reg; bf16 partials
    __bf16* Cb = Cp + (size_t)blockIdx.z * CPE;
#pragma unroll
    for (int mi = 0; mi < 4; ++mi) {
        const int row = m0 + wm * 64 + mi * 16 + q * 4;
#pragma unroll
        for (int ni = 0; ni < 4; ++ni) {
            const int col = n0 + wn * 64 + ni * 16 + r16;
#pragma unroll
            for (int r = 0; r < 4; ++r)
                Cb[(size_t)(row + r) * 512 + col] = (__bf16)acc[mi][ni][r];
        }
    }
}

// ---- kernel 3: sum 8 bf16 partials + LayerNorm, one wave per row ----------
__global__ void ln_kernel(const __bf16* __restrict__ Cp, const float* __restrict__ gamma,
                          const float* __restrict__ beta, float* __restrict__ out) {
    const int tid  = threadIdx.x;
    const int wave = tid >> 6, lane = tid & 63;
    const int row  = blockIdx.x * 4 + wave;
    const size_t base = (size_t)row * 512 + lane * 8;   // 8 contiguous cols/lane

    float v[8] = {};
    float s = 0.f, s2 = 0.f;
#pragma unroll
    for (int z = 0; z < SPLITS; ++z) {
        bf16x8 p = *(const bf16x8*)(Cp + (size_t)z * CPE + base);
#pragma unroll
        for (int j = 0; j < 8; ++j) v[j] += (float)p[j];
    }
#pragma unroll
    for (int j = 0; j < 8; ++j) { s += v[j]; s2 += v[j] * v[j]; }
#pragma unroll
    for (int m = 32; m >= 1; m >>= 1) {
        s  += __shfl_xor(s, m);
        s2 += __shfl_xor(s2, m);
    }
    const float mean = s * (1.0f / 512.0f);
    const float var  = s2 * (1.0f / 512.0f) - mean * mean;
    const float rs   = rsqrtf(var + 1e-5f);
    float4 o0, o1;
    const float4 g0 = *(const float4*)&gamma[lane * 8];
    const float4 g1 = *(const float4*)&gamma[lane * 8 + 4];
    const float4 b0 = *(const float4*)&beta[lane * 8];
    const float4 b1 = *(const float4*)&beta[lane * 8 + 4];
    o0.x = (v[0] - mean) * rs * g0.x + b0.x;
    o0.y = (v[1] - mean) * rs * g0.y + b0.y;
    o0.z = (v[2] - mean) * rs * g0.z + b0.z;
    o0.w = (v[3] - mean) * rs * g0.w + b0.w;
    o1.x = (v[4] - mean) * rs * g1.x + b1.x;
    o1.y = (v[5] - mean) * rs * g1.y + b1.y;
    o1.z = (v[6] - mean) * rs * g1.z + b1.z;
    o1.w = (v[7] - mean) * rs * g1.w + b1.w;
    *(float4*)&out[base]     = o0;
    *(float4*)&out[base + 4] = o1;
}

extern "C" void kernel_launch(void* const* d_in, const int* in_sizes, int n_in,
                              void* d_out, int out_size, void* d_ws, size_t ws_size,
                              hipStream_t stream) {
    const float* x     = (const float*)d_in[0];
    const float* W     = (const float*)d_in[1];
    const float* Wb    = (const float*)d_in[2];
    const float* gamma = (const float*)d_in[3];
    const float* beta  = (const float*)d_in[4];
    float* out = (float*)d_out;

    char* ws = (char*)d_ws;
    __bf16* A  = (__bf16*)ws;                        // 71,303,168 B
    __bf16* Bm = (__bf16*)(ws + 71303168);           //  8,912,896 B
    __bf16* Cp = (__bf16*)(ws + 80216064);           // 33,554,432 B

    prep_AB<<<8192 + 4352, 256, 0, stream>>>(x, W, Wb, A, Bm);
    dim3 g(32, 4, SPLITS);
    gemm_bt<<<g, 256, 0, stream>>>(A, Bm, Cp);
    ln_kernel<<<1024, 256, 0, stream>>>(Cp, gamma, beta, out);
}

// Round 2
// 150.741 us; speedup vs baseline: 1.0099x; 1.0099x over previous
//
#include <hip/hip_runtime.h>
#include <hip/hip_bf16.h>

// KAN layer: out = einsum('bik,jik->bj', rbf(x), W) + silu(x)@Wb^T, then LN.
// GEMM view: C[4096,512] = A[4096,8704] * B[512,8704]^T in bf16 MFMA.
//
// d_ws layout (113,770,496 B total):
//   A  bf16 [4096][8704]     @ 0          (71,303,168 B)  A = [basis | silu(x)]
//   Bm bf16 [512][8704]      @ 71303168   ( 8,912,896 B)  Bm = [W | Wb]
//   Cp bf16 [8][4096][512]   @ 80216064   (33,554,432 B)  split-K partials (bf16)

typedef __bf16 bf16x8 __attribute__((ext_vector_type(8)));
typedef __bf16 bf16x4 __attribute__((ext_vector_type(4)));
typedef float  f32x4  __attribute__((ext_vector_type(4)));

#define KT 8704            // total K = 512*16 + 512
#define SPLITS 8
#define KS (KT / SPLITS)   // 1088 = 34 iters of BK=32
#define NIT (KS / 32)
#define CPE (4096 * 512)   // elements per partial
#define ABUF (256 * 32)    // one ring buffer per matrix: 256 rows x 32 k, elems

__device__ __forceinline__ void gll16(const __bf16* g, __bf16* l) {
    __builtin_amdgcn_global_load_lds(
        (const __attribute__((address_space(1))) void*)g,
        (__attribute__((address_space(3))) void*)l, 16, 0, 0);
}

// ---- kernel 1: A = [rbf basis | silu(x)], Bm = [W | Wb], both bf16 --------
// centers linspace(-2,2,16), h = 4/15 => z_k = 3.75x + 7.5 - k
__global__ void prep_AB(const float* __restrict__ x, const float* __restrict__ W,
                        const float* __restrict__ Wb, __bf16* __restrict__ A,
                        __bf16* __restrict__ B) {
    if (blockIdx.x < 8192) {                     // A-part: 1 thread per x elem
        int t = blockIdx.x * 256 + threadIdx.x;  // 0 .. 4096*512
        int b = t >> 9;
        int i = t & 511;
        float xv = x[t];
        float zb = 3.75f * xv + 7.5f;
        bf16x8 lo, hi;
#pragma unroll
        for (int k = 0; k < 8; ++k) { float z = zb - (float)k; lo[k]   = (__bf16)__expf(-z * z); }
#pragma unroll
        for (int k = 8; k < 16; ++k){ float z = zb - (float)k; hi[k-8] = (__bf16)__expf(-z * z); }
        size_t base = (size_t)b * KT + (size_t)i * 16;
        *(bf16x8*)(A + base)     = lo;
        *(bf16x8*)(A + base + 8) = hi;
        float s = xv / (1.0f + __expf(-xv));     // silu
        A[(size_t)b * KT + 8192 + i] = (__bf16)s;
    } else {                                     // B-part: cast W|Wb, 4 elems/thread
        int t = (blockIdx.x - 8192) * 256 + threadIdx.x;  // 0 .. 512*2176
        int j = t / 2176;
        int c = (t - j * 2176) * 4;
        float4 v;
        if (c < 8192) v = *(const float4*)&W[(size_t)j * 8192 + c];
        else          v = *(const float4*)&Wb[(size_t)j * 512 + (c - 8192)];
        bf16x4 o;
        o[0] = (__bf16)v.x; o[1] = (__bf16)v.y; o[2] = (__bf16)v.z; o[3] = (__bf16)v.w;
        *(bf16x4*)&B[(size_t)j * KT + c] = o;
    }
}

// ---- kernel 2: split-K GEMM, 256x256 tile, 8 waves, BK=32 -----------------
// R1 post-mortem: 128x128/4-wave geometry has FLOP/LDS-byte = 32 -> per CU
// per iter the LDS pipe (192KB @ ~112-128 B/cyc = 1500-1700 cyc) outweighs
// the MFMA pipe (1030 cyc); MfmaUtil capped ~26% regardless of pipelining.
// R1's 3-buffer ring also broke grid fit (1024 blocks @ 3/CU -> straggler
// round, occupancy 32->21%).
// This version: BM=BN=256, 8 waves (2x4), per-wave 128x64 -> FLOP/LDS-byte
// 42.7; per CU per iter LDS = 128KB (~1100 cyc) < ... ~= MFMA 1030 cyc.
// Grid 16x2x8 = 256 blocks = exactly 1/CU (96KB LDS), zero tail.
// Keep R1's proven counted-vmcnt ring: 3 buffers, distance-2 prefetch,
// vmcnt(4) + raw s_barrier, never drained to 0 in the loop.
// LDS chunk swizzle (proven 0-conflict): 16B chunk (row, qk) stored at
// chunk index row*4 + (qk ^ ((row>>1)&3)); reads de-swizzle with
// qa = q ^ ((r16>>1)&3).
__global__ __launch_bounds__(512, 2) void gemm_bt(const __bf16* __restrict__ A,
                                                  const __bf16* __restrict__ B,
                                                  __bf16* __restrict__ Cp) {
    __shared__ __attribute__((aligned(16))) __bf16 As[3 * ABUF];
    __shared__ __attribute__((aligned(16))) __bf16 Bs[3 * ABUF];

    const int tid  = threadIdx.x;
    const int wave = tid >> 6, lane = tid & 63;
    const int q    = lane >> 4, r16 = lane & 15;
    const int m0 = blockIdx.x * 256, n0 = blockIdx.y * 256, k0 = blockIdx.z * KS;
    const int wm = wave >> 2, wn = wave & 3;     // 2x4 waves; per-wave 128x64 out

    // staging: chunk g (0..1023 per tile) holds global (row=g>>2, qk=(g&3)^((row>>1)&3)).
    // thread t covers chunks t and t+512 (rows srow, srow+128; same qk since 128>>1=64 ≡ 0 mod 4).
    const int srow = tid >> 2, sqk = (tid & 3) ^ ((srow >> 1) & 3);
    const __bf16* gA0 = A + (size_t)(m0 + srow) * KT + k0 + sqk * 8;
    const __bf16* gA1 = A + (size_t)(m0 + srow + 128) * KT + k0 + sqk * 8;
    const __bf16* gB0 = B + (size_t)(n0 + srow) * KT + k0 + sqk * 8;
    const __bf16* gB1 = B + (size_t)(n0 + srow + 128) * KT + k0 + sqk * 8;

    f32x4 acc[8][4] = {};

    const int qa    = q ^ ((r16 >> 1) & 3);      // de-swizzle for reads
    const int awOff = (wm * 128 + r16) * 32 + qa * 8;
    const int bwOff = (wn * 64  + r16) * 32 + qa * 8;

    // stage tile t into ring buffer sb: 4 gll16/thread = 4 vmcnt slots/wave.
    // Tail prefetch (t >= NIT) reads <=80 elems past the K-slice / array end
    // but stays inside mapped ws (spills into the next ws region); never consumed.
    auto stage = [&](int t, int sb) {
        const int ko = t * 32;
        const int so = sb * ABUF;
        gll16(gA0 + ko, &As[so + tid * 8]);
        gll16(gA1 + ko, &As[so + (tid + 512) * 8]);
        gll16(gB0 + ko, &Bs[so + tid * 8]);
        gll16(gB1 + ko, &Bs[so + (tid + 512) * 8]);
    };

    auto compute = [&](int cb) {
        const __bf16* Aw = &As[cb * ABUF + awOff];
        const __bf16* Bw = &Bs[cb * ABUF + bwOff];
        bf16x8 af[8], bg[4];
#pragma unroll
        for (int mi = 0; mi < 8; ++mi) af[mi] = *(const bf16x8*)(Aw + mi * 512);
#pragma unroll
        for (int ni = 0; ni < 4; ++ni) bg[ni] = *(const bf16x8*)(Bw + ni * 512);
        __builtin_amdgcn_s_setprio(1);           // T5: MFMA cluster priority
#pragma unroll
        for (int mi = 0; mi < 8; ++mi)
#pragma unroll
            for (int ni = 0; ni < 4; ++ni)
                acc[mi][ni] = __builtin_amdgcn_mfma_f32_16x16x32_bf16(
                    af[mi], bg[ni], acc[mi][ni], 0, 0, 0);
        __builtin_amdgcn_s_setprio(0);
    };

    // prologue: tiles 0,1 in flight (8 loads/wave); wait tile 0 only (vmcnt(4)).
    stage(0, 0);
    stage(1, 1);
    asm volatile("s_waitcnt vmcnt(4)" ::: "memory");
    __builtin_amdgcn_s_barrier();

    int cb = 0;                                  // compute buffer = it % 3
    for (int it = 0; it < NIT - 1; ++it) {
        int sb = cb - 1; if (sb < 0) sb = 2;     // (it+2) % 3 — freed at end of it-1
        stage(it + 2, sb);                       // issue-only; stays in flight
        compute(cb);
        // counted wait: of 8 outstanding loads, require oldest 4 (tile it+1)
        // done; tile it+2's 4 remain in flight ACROSS the barrier. The barrier
        // aggregates the per-wave guarantee to the whole block.
        asm volatile("s_waitcnt vmcnt(4)" ::: "memory");
        __builtin_amdgcn_s_barrier();
        cb = (cb == 2) ? 0 : cb + 1;
    }
    compute(cb);                                 // last tile: already waited

    // epilogue: C/D layout col=lane&15, row=(lane>>4)*4+reg; bf16 partials
    __bf16* Cb = Cp + (size_t)blockIdx.z * CPE;
#pragma unroll
    for (int mi = 0; mi < 8; ++mi) {
        const int row = m0 + wm * 128 + mi * 16 + q * 4;
#pragma unroll
        for (int ni = 0; ni < 4; ++ni) {
            const int col = n0 + wn * 64 + ni * 16 + r16;
#pragma unroll
            for (int r = 0; r < 4; ++r)
                Cb[(size_t)(row + r) * 512 + col] = (__bf16)acc[mi][ni][r];
        }
    }
}

// ---- kernel 3: sum 8 bf16 partials + LayerNorm, one wave per row ----------
__global__ void ln_kernel(const __bf16* __restrict__ Cp, const float* __restrict__ gamma,
                          const float* __restrict__ beta, float* __restrict__ out) {
    const int tid  = threadIdx.x;
    const int wave = tid >> 6, lane = tid & 63;
    const int row  = blockIdx.x * 4 + wave;
    const size_t base = (size_t)row * 512 + lane * 8;   // 8 contiguous cols/lane

    float v[8] = {};
    float s = 0.f, s2 = 0.f;
#pragma unroll
    for (int z = 0; z < SPLITS; ++z) {
        bf16x8 p = *(const bf16x8*)(Cp + (size_t)z * CPE + base);
#pragma unroll
        for (int j = 0; j < 8; ++j) v[j] += (float)p[j];
    }
#pragma unroll
    for (int j = 0; j < 8; ++j) { s += v[j]; s2 += v[j] * v[j]; }
#pragma unroll
    for (int m = 32; m >= 1; m >>= 1) {
        s  += __shfl_xor(s, m);
        s2 += __shfl_xor(s2, m);
    }
    const float mean = s * (1.0f / 512.0f);
    const float var  = s2 * (1.0f / 512.0f) - mean * mean;
    const float rs   = rsqrtf(var + 1e-5f);
    float4 o0, o1;
    const float4 g0 = *(const float4*)&gamma[lane * 8];
    const float4 g1 = *(const float4*)&gamma[lane * 8 + 4];
    const float4 b0 = *(const float4*)&beta[lane * 8];
    const float4 b1 = *(const float4*)&beta[lane * 8 + 4];
    o0.x = (v[0] - mean) * rs * g0.x + b0.x;
    o0.y = (v[1] - mean) * rs * g0.y + b0.y;
    o0.z = (v[2] - mean) * rs * g0.z + b0.z;
    o0.w = (v[3] - mean) * rs * g0.w + b0.w;
    o1.x = (v[4] - mean) * rs * g1.x + b1.x;
    o1.y = (v[5] - mean) * rs * g1.y + b1.y;
    o1.z = (v[6] - mean) * rs * g1.z + b1.z;
    o1.w = (v[7] - mean) * rs * g1.w + b1.w;
    *(float4*)&out[base]     = o0;
    *(float4*)&out[base + 4] = o1;
}

extern "C" void kernel_launch(void* const* d_in, const int* in_sizes, int n_in,
                              void* d_out, int out_size, void* d_ws, size_t ws_size,
                              hipStream_t stream) {
    const float* x     = (const float*)d_in[0];
    const float* W     = (const float*)d_in[1];
    const float* Wb    = (const float*)d_in[2];
    const float* gamma = (const float*)d_in[3];
    const float* beta  = (const float*)d_in[4];
    float* out = (float*)d_out;

    char* ws = (char*)d_ws;
    __bf16* A  = (__bf16*)ws;                        // 71,303,168 B
    __bf16* Bm = (__bf16*)(ws + 71303168);           //  8,912,896 B
    __bf16* Cp = (__bf16*)(ws + 80216064);           // 33,554,432 B

    prep_AB<<<8192 + 4352, 256, 0, stream>>>(x, W, Wb, A, Bm);
    dim3 g(16, 2, SPLITS);
    gemm_bt<<<g, 512, 0, stream>>>(A, Bm, Cp);
    ln_kernel<<<1024, 256, 0, stream>>>(Cp, gamma, beta, out);
}

// Round 3
// 141.722 us; speedup vs baseline: 1.0742x; 1.0636x over previous
//
#include <hip/hip_runtime.h>
#include <hip/hip_bf16.h>

// KAN layer: out = einsum('bik,jik->bj', rbf(x), W) + silu(x)@Wb^T, then LN.
// GEMM view: C[4096,512] = A[4096,8704] * B[512,8704]^T in bf16 MFMA.
//
// d_ws layout (113,770,496 B total):
//   A  bf16 [4096][8704]     @ 0          (71,303,168 B)  A = [basis | silu(x)]
//   Bm bf16 [512][8704]      @ 71303168   ( 8,912,896 B)  Bm = [W | Wb]
//   Cp bf16 [8][4096][512]   @ 80216064   (33,554,432 B)  split-K partials (bf16)

typedef __bf16 bf16x8 __attribute__((ext_vector_type(8)));
typedef __bf16 bf16x4 __attribute__((ext_vector_type(4)));
typedef float  f32x4  __attribute__((ext_vector_type(4)));

#define KT 8704            // total K = 512*16 + 512
#define SPLITS 8
#define KS (KT / SPLITS)   // 1088 per z-block
#define NT2 (KS / 64)      // 17 K-tiles of BK=64
#define CPE (4096 * 512)   // elements per partial
#define ATILE (256 * 64)   // one tile slot per matrix: 256 rows x 64 k, elems

__device__ __forceinline__ void gll16(const __bf16* g, __bf16* l) {
    __builtin_amdgcn_global_load_lds(
        (const __attribute__((address_space(1))) void*)g,
        (__attribute__((address_space(3))) void*)l, 16, 0, 0);
}

// ---- kernel 1: A = [rbf basis | silu(x)], Bm = [W | Wb], both bf16 --------
// centers linspace(-2,2,16), h = 4/15 => z_k = 3.75x + 7.5 - k
__global__ void prep_AB(const float* __restrict__ x, const float* __restrict__ W,
                        const float* __restrict__ Wb, __bf16* __restrict__ A,
                        __bf16* __restrict__ B) {
    if (blockIdx.x < 8192) {                     // A-part: 1 thread per x elem
        int t = blockIdx.x * 256 + threadIdx.x;  // 0 .. 4096*512
        int b = t >> 9;
        int i = t & 511;
        float xv = x[t];
        float zb = 3.75f * xv + 7.5f;
        bf16x8 lo, hi;
#pragma unroll
        for (int k = 0; k < 8; ++k) { float z = zb - (float)k; lo[k]   = (__bf16)__expf(-z * z); }
#pragma unroll
        for (int k = 8; k < 16; ++k){ float z = zb - (float)k; hi[k-8] = (__bf16)__expf(-z * z); }
        size_t base = (size_t)b * KT + (size_t)i * 16;
        *(bf16x8*)(A + base)     = lo;
        *(bf16x8*)(A + base + 8) = hi;
        float s = xv / (1.0f + __expf(-xv));     // silu
        A[(size_t)b * KT + 8192 + i] = (__bf16)s;
    } else {                                     // B-part: cast W|Wb, 4 elems/thread
        int t = (blockIdx.x - 8192) * 256 + threadIdx.x;  // 0 .. 512*2176
        int j = t / 2176;
        int c = (t - j * 2176) * 4;
        float4 v;
        if (c < 8192) v = *(const float4*)&W[(size_t)j * 8192 + c];
        else          v = *(const float4*)&Wb[(size_t)j * 512 + (c - 8192)];
        bf16x4 o;
        o[0] = (__bf16)v.x; o[1] = (__bf16)v.y; o[2] = (__bf16)v.z; o[3] = (__bf16)v.w;
        *(bf16x4*)&B[(size_t)j * KT + c] = o;
    }
}

// ---- kernel 2: split-K GEMM, 256x256 tile, 8 waves, BK=64, 4-phase --------
// R2 post-mortem: any single-barrier-pair-per-K-step loop sits at the known
// "2-phase ceiling" (~607 TF, m233) regardless of tile geometry: stage+vmcnt+
// barrier serialize with compute. Proven exit = m201's phase-split schedule:
// small {ds_read || 2 gll16 -> barrier -> lgkmcnt(0) -> setprio MFMA ->
// barrier} phases, vmcnt counted ONCE per K-tile (never 0 in the loop).
//
// 4 phases per K-tile (BK=64): ph0 (ks0, mi0-3 + B ks0), ph1 (ks0, mi4-7),
// ph2 (ks1, mi0-3 + B ks1), ph3 (ks1, mi4-7). 16 MFMA each.
// Staging (2 gll16/phase/thread): ph0/ph1 -> B of tile u+1 (free slot),
// ph2 -> A rows[64..127]+[192..255] of u+1 (free slot), ph3 -> A rows
// [0..63]+[128..191] of tile u+2 into the CURRENT slot (those rows' last
// reads are ph2's, completed before ph2's end barrier). vmcnt(2) before the
// tile-end barrier: drains tile u+1's 8 loads, leaves u+2's 2 in flight.
//
// LDS swizzle: row of 8 16B-chunks, chunk col c stored at c ^ ((row>>1)&7).
// Per 16-lane read group: 8 distinct chunk slots x 2 lanes = 2/bank = free.
// (The R2 4-way scheme would be a 4-way conflict at BK=64 since ks is
// instruction-uniform.)
__global__ __launch_bounds__(512, 2) void gemm_bt(const __bf16* __restrict__ A,
                                                  const __bf16* __restrict__ B,
                                                  __bf16* __restrict__ Cp) {
    __shared__ __attribute__((aligned(16))) __bf16 As[2 * ATILE];
    __shared__ __attribute__((aligned(16))) __bf16 Bs[2 * ATILE];

    const int tid  = threadIdx.x;
    const int wave = tid >> 6, lane = tid & 63;
    const int q    = lane >> 4, r16 = lane & 15;
    const int m0 = blockIdx.x * 256, n0 = blockIdx.y * 256, k0 = blockIdx.z * KS;
    const int wm = wave >> 2, wn = wave & 3;     // 2x4 waves; per-wave 128x64 out

    // staging: per matrix, tile = 2048 chunks of 16B; chunk g: row=g>>3, pos=g&7,
    // source col c = pos ^ ((row>>1)&7). Thread t covers chunks t, 512+t,
    // 1024+t, 1536+t (row groups 0/64/128/192; same c since offsets = 0 mod 8).
    const int sr = tid >> 3;                           // 0..63
    const int sc = (tid & 7) ^ ((tid >> 4) & 7);       // de-swizzled source col
    const __bf16* gA0 = A + (size_t)(m0 + sr) * KT       + k0 + sc * 8; // rows   0- 63
    const __bf16* gA1 = A + (size_t)(m0 + 64  + sr) * KT + k0 + sc * 8; // rows  64-127
    const __bf16* gA2 = A + (size_t)(m0 + 128 + sr) * KT + k0 + sc * 8; // rows 128-191
    const __bf16* gA3 = A + (size_t)(m0 + 192 + sr) * KT + k0 + sc * 8; // rows 192-255
    const __bf16* gB0 = B + (size_t)(n0 + sr) * KT       + k0 + sc * 8;
    const __bf16* gB1 = B + (size_t)(n0 + 64  + sr) * KT + k0 + sc * 8;
    const __bf16* gB2 = B + (size_t)(n0 + 128 + sr) * KT + k0 + sc * 8;
    const __bf16* gB3 = B + (size_t)(n0 + 192 + sr) * KT + k0 + sc * 8;

    f32x4 acc[8][4] = {};

    // read offsets (elements). swl = (row>>1)&7 reduces to (r16>>1)&7 for all
    // row bases used (wm*128, wn*64, mi*16, ni*16 are all 0 mod 16).
    const int swl = (r16 >> 1) & 7;
    const int qx0 = ((q)     ^ swl) * 8;         // ks=0 chunk
    const int qx1 = ((4 + q) ^ swl) * 8;         // ks=1 chunk
    const int aro = (wm * 128 + r16) * 64;
    const int bro = (wn * 64  + r16) * 64;

    // prologue: tile 0 full (8 loads) + tile 1's A-X rows (2 loads) in order.
    gll16(gA0, &As[(size_t)tid * 8]);
    gll16(gA1, &As[(size_t)(512 + tid) * 8]);
    gll16(gA2, &As[(size_t)(1024 + tid) * 8]);
    gll16(gA3, &As[(size_t)(1536 + tid) * 8]);
    gll16(gB0, &Bs[(size_t)tid * 8]);
    gll16(gB1, &Bs[(size_t)(512 + tid) * 8]);
    gll16(gB2, &Bs[(size_t)(1024 + tid) * 8]);
    gll16(gB3, &Bs[(size_t)(1536 + tid) * 8]);
    gll16(gA0 + 64, &As[(size_t)(ATILE + tid * 8)]);
    gll16(gA2 + 64, &As[(size_t)(ATILE + (1024 + tid) * 8)]);
    asm volatile("s_waitcnt vmcnt(2)" ::: "memory");   // tile 0 resident
    __builtin_amdgcn_s_barrier();

    bf16x8 a[4], b[4];
    for (int u = 0; u < NT2; ++u) {
        const int s   = u & 1;
        const int cbo = s * ATILE;               // compute slot (tile u)
        const int so1 = (s ^ 1) * ATILE;         // slot for tile u+1
        const int k1  = (u + 1) * 64;
        const int k2  = (u + 2) * 64;
        // Tail (u+1/u+2 >= NT2): sources read <=256 B past A/B row ends but
        // stay inside mapped ws (spill into next ws region); never consumed.

        // -------- phase 0: ks=0, mi 0..3 (8 ds_read) --------
#pragma unroll
        for (int mi = 0; mi < 4; ++mi) a[mi] = *(const bf16x8*)(As + cbo + aro + mi * 1024 + qx0);
#pragma unroll
        for (int ni = 0; ni < 4; ++ni) b[ni] = *(const bf16x8*)(Bs + cbo + bro + ni * 1024 + qx0);
        gll16(gB0 + k1, &Bs[(size_t)(so1 + tid * 8)]);
        gll16(gB1 + k1, &Bs[(size_t)(so1 + (512 + tid) * 8)]);
        __builtin_amdgcn_s_barrier();
        asm volatile("s_waitcnt lgkmcnt(0)" ::: "memory");
        __builtin_amdgcn_sched_barrier(0);
        __builtin_amdgcn_s_setprio(1);
#pragma unroll
        for (int mi = 0; mi < 4; ++mi)
#pragma unroll
            for (int ni = 0; ni < 4; ++ni)
                acc[mi][ni] = __builtin_amdgcn_mfma_f32_16x16x32_bf16(a[mi], b[ni], acc[mi][ni], 0, 0, 0);
        __builtin_amdgcn_s_setprio(0);
        __builtin_amdgcn_s_barrier();

        // -------- phase 1: ks=0, mi 4..7 (4 ds_read, reuse b) --------
#pragma unroll
        for (int mi = 0; mi < 4; ++mi) a[mi] = *(const bf16x8*)(As + cbo + aro + (4 + mi) * 1024 + qx0);
        gll16(gB2 + k1, &Bs[(size_t)(so1 + (1024 + tid) * 8)]);
        gll16(gB3 + k1, &Bs[(size_t)(so1 + (1536 + tid) * 8)]);
        __builtin_amdgcn_s_barrier();
        asm volatile("s_waitcnt lgkmcnt(0)" ::: "memory");
        __builtin_amdgcn_sched_barrier(0);
        __builtin_amdgcn_s_setprio(1);
#pragma unroll
        for (int mi = 0; mi < 4; ++mi)
#pragma unroll
            for (int ni = 0; ni < 4; ++ni)
                acc[4 + mi][ni] = __builtin_amdgcn_mfma_f32_16x16x32_bf16(a[mi], b[ni], acc[4 + mi][ni], 0, 0, 0);
        __builtin_amdgcn_s_setprio(0);
        __builtin_amdgcn_s_barrier();

        // -------- phase 2: ks=1, mi 0..3 (8 ds_read) --------
#pragma unroll
        for (int mi = 0; mi < 4; ++mi) a[mi] = *(const bf16x8*)(As + cbo + aro + mi * 1024 + qx1);
#pragma unroll
        for (int ni = 0; ni < 4; ++ni) b[ni] = *(const bf16x8*)(Bs + cbo + bro + ni * 1024 + qx1);
        gll16(gA1 + k1, &As[(size_t)(so1 + (512 + tid) * 8)]);
        gll16(gA3 + k1, &As[(size_t)(so1 + (1536 + tid) * 8)]);
        __builtin_amdgcn_s_barrier();
        asm volatile("s_waitcnt lgkmcnt(0)" ::: "memory");
        __builtin_amdgcn_sched_barrier(0);
        __builtin_amdgcn_s_setprio(1);
#pragma unroll
        for (int mi = 0; mi < 4; ++mi)
#pragma unroll
            for (int ni = 0; ni < 4; ++ni)
                acc[mi][ni] = __builtin_amdgcn_mfma_f32_16x16x32_bf16(a[mi], b[ni], acc[mi][ni], 0, 0, 0);
        __builtin_amdgcn_s_setprio(0);
        __builtin_amdgcn_s_barrier();

        // -------- phase 3: ks=1, mi 4..7 (4 ds_read, reuse b) --------
        // stage tile u+2's A rows [0..63]+[128..191] into the CURRENT slot:
        // their last reads were phase 2's (ks=1), completed before ph2's
        // end barrier, so the DMA writes cannot race the reads.
#pragma unroll
        for (int mi = 0; mi < 4; ++mi) a[mi] = *(const bf16x8*)(As + cbo + aro + (4 + mi) * 1024 + qx1);
        gll16(gA0 + k2, &As[(size_t)(cbo + tid * 8)]);
        gll16(gA2 + k2, &As[(size_t)(cbo + (1024 + tid) * 8)]);
        __builtin_amdgcn_s_barrier();
        asm volatile("s_waitcnt lgkmcnt(0)" ::: "memory");
        __builtin_amdgcn_sched_barrier(0);
        __builtin_amdgcn_s_setprio(1);
#pragma unroll
        for (int mi = 0; mi < 4; ++mi)
#pragma unroll
            for (int ni = 0; ni < 4; ++ni)
                acc[4 + mi][ni] = __builtin_amdgcn_mfma_f32_16x16x32_bf16(a[mi], b[ni], acc[4 + mi][ni], 0, 0, 0);
        __builtin_amdgcn_s_setprio(0);
        // counted per-tile wait: outstanding = tile u+1's 8 + tile u+2's 2;
        // drain to 2 -> tile u+1 resident, u+2's A-X stays in flight.
        asm volatile("s_waitcnt vmcnt(2)" ::: "memory");
        __builtin_amdgcn_s_barrier();
    }

    // epilogue: C/D layout col=lane&15, row=(lane>>4)*4+reg; bf16 partials
    __bf16* Cb = Cp + (size_t)blockIdx.z * CPE;
#pragma unroll
    for (int mi = 0; mi < 8; ++mi) {
        const int row = m0 + wm * 128 + mi * 16 + q * 4;
#pragma unroll
        for (int ni = 0; ni < 4; ++ni) {
            const int col = n0 + wn * 64 + ni * 16 + r16;
#pragma unroll
            for (int r = 0; r < 4; ++r)
                Cb[(size_t)(row + r) * 512 + col] = (__bf16)acc[mi][ni][r];
        }
    }
}

// ---- kernel 3: sum 8 bf16 partials + LayerNorm, one wave per row ----------
__global__ void ln_kernel(const __bf16* __restrict__ Cp, const float* __restrict__ gamma,
                          const float* __restrict__ beta, float* __restrict__ out) {
    const int tid  = threadIdx.x;
    const int wave = tid >> 6, lane = tid & 63;
    const int row  = blockIdx.x * 4 + wave;
    const size_t base = (size_t)row * 512 + lane * 8;   // 8 contiguous cols/lane

    float v[8] = {};
    float s = 0.f, s2 = 0.f;
#pragma unroll
    for (int z = 0; z < SPLITS; ++z) {
        bf16x8 p = *(const bf16x8*)(Cp + (size_t)z * CPE + base);
#pragma unroll
        for (int j = 0; j < 8; ++j) v[j] += (float)p[j];
    }
#pragma unroll
    for (int j = 0; j < 8; ++j) { s += v[j]; s2 += v[j] * v[j]; }
#pragma unroll
    for (int m = 32; m >= 1; m >>= 1) {
        s  += __shfl_xor(s, m);
        s2 += __shfl_xor(s2, m);
    }
    const float mean = s * (1.0f / 512.0f);
    const float var  = s2 * (1.0f / 512.0f) - mean * mean;
    const float rs   = rsqrtf(var + 1e-5f);
    float4 o0, o1;
    const float4 g0 = *(const float4*)&gamma[lane * 8];
    const float4 g1 = *(const float4*)&gamma[lane * 8 + 4];
    const float4 b0 = *(const float4*)&beta[lane * 8];
    const float4 b1 = *(const float4*)&beta[lane * 8 + 4];
    o0.x = (v[0] - mean) * rs * g0.x + b0.x;
    o0.y = (v[1] - mean) * rs * g0.y + b0.y;
    o0.z = (v[2] - mean) * rs * g0.z + b0.z;
    o0.w = (v[3] - mean) * rs * g0.w + b0.w;
    o1.x = (v[4] - mean) * rs * g1.x + b1.x;
    o1.y = (v[5] - mean) * rs * g1.y + b1.y;
    o1.z = (v[6] - mean) * rs * g1.z + b1.z;
    o1.w = (v[7] - mean) * rs * g1.w + b1.w;
    *(float4*)&out[base]     = o0;
    *(float4*)&out[base + 4] = o1;
}

extern "C" void kernel_launch(void* const* d_in, const int* in_sizes, int n_in,
                              void* d_out, int out_size, void* d_ws, size_t ws_size,
                              hipStream_t stream) {
    const float* x     = (const float*)d_in[0];
    const float* W     = (const float*)d_in[1];
    const float* Wb    = (const float*)d_in[2];
    const float* gamma = (const float*)d_in[3];
    const float* beta  = (const float*)d_in[4];
    float* out = (float*)d_out;

    char* ws = (char*)d_ws;
    __bf16* A  = (__bf16*)ws;                        // 71,303,168 B
    __bf16* Bm = (__bf16*)(ws + 71303168);           //  8,912,896 B
    __bf16* Cp = (__bf16*)(ws + 80216064);           // 33,554,432 B

    prep_AB<<<8192 + 4352, 256, 0, stream>>>(x, W, Wb, A, Bm);
    dim3 g(16, 2, SPLITS);
    gemm_bt<<<g, 512, 0, stream>>>(A, Bm, Cp);
    ln_kernel<<<1024, 256, 0, stream>>>(Cp, gamma, beta, out);
}

// Round 4
// 136.591 us; speedup vs baseline: 1.1145x; 1.0376x over previous
//
#include <hip/hip_runtime.h>
#include <hip/hip_bf16.h>

// KAN layer: out = einsum('bik,jik->bj', rbf(x), W) + silu(x)@Wb^T, then LN.
// GEMM view: C[4096,512] = A[4096,8704] * B[512,8704]^T in bf16 MFMA.
//
// d_ws layout (113,770,496 B total):
//   A  bf16 [4096][8704]     @ 0          (71,303,168 B)  A = [basis | silu(x)]
//   Bm bf16 [512][8704]      @ 71303168   ( 8,912,896 B)  Bm = [W | Wb]
//   Cp bf16 [8][4096][512]   @ 80216064   (33,554,432 B)  split-K partials (bf16)

typedef __bf16 bf16x8 __attribute__((ext_vector_type(8)));
typedef __bf16 bf16x4 __attribute__((ext_vector_type(4)));
typedef float  f32x4  __attribute__((ext_vector_type(4)));

#define KT 8704            // total K = 512*16 + 512
#define SPLITS 8
#define KS (KT / SPLITS)   // 1088 per z-block
#define NT2 (KS / 64)      // 17 K-tiles of BK=64
#define CPE (4096 * 512)   // elements per partial
#define ATILE (256 * 64)   // one tile slot per matrix: 256 rows x 64 k, elems

__device__ __forceinline__ void gll16(const __bf16* g, __bf16* l) {
    __builtin_amdgcn_global_load_lds(
        (const __attribute__((address_space(1))) void*)g,
        (__attribute__((address_space(3))) void*)l, 16, 0, 0);
}

// ---- kernel 1: A = [rbf basis | silu(x)], Bm = [W | Wb], both bf16 --------
// centers linspace(-2,2,16), h = 4/15 => z_k = 3.75x + 7.5 - k
__global__ void prep_AB(const float* __restrict__ x, const float* __restrict__ W,
                        const float* __restrict__ Wb, __bf16* __restrict__ A,
                        __bf16* __restrict__ B) {
    if (blockIdx.x < 8192) {                     // A-part: 1 thread per x elem
        int t = blockIdx.x * 256 + threadIdx.x;  // 0 .. 4096*512
        int b = t >> 9;
        int i = t & 511;
        float xv = x[t];
        float zb = 3.75f * xv + 7.5f;
        bf16x8 lo, hi;
#pragma unroll
        for (int k = 0; k < 8; ++k) { float z = zb - (float)k; lo[k]   = (__bf16)__expf(-z * z); }
#pragma unroll
        for (int k = 8; k < 16; ++k){ float z = zb - (float)k; hi[k-8] = (__bf16)__expf(-z * z); }
        size_t base = (size_t)b * KT + (size_t)i * 16;
        *(bf16x8*)(A + base)     = lo;
        *(bf16x8*)(A + base + 8) = hi;
        float s = xv / (1.0f + __expf(-xv));     // silu
        A[(size_t)b * KT + 8192 + i] = (__bf16)s;
    } else {                                     // B-part: cast W|Wb, 4 elems/thread
        int t = (blockIdx.x - 8192) * 256 + threadIdx.x;  // 0 .. 512*2176
        int j = t / 2176;
        int c = (t - j * 2176) * 4;
        float4 v;
        if (c < 8192) v = *(const float4*)&W[(size_t)j * 8192 + c];
        else          v = *(const float4*)&Wb[(size_t)j * 512 + (c - 8192)];
        bf16x4 o;
        o[0] = (__bf16)v.x; o[1] = (__bf16)v.y; o[2] = (__bf16)v.z; o[3] = (__bf16)v.w;
        *(bf16x4*)&B[(size_t)j * KT + c] = o;
    }
}

// ---- kernel 2: split-K GEMM, 256x256 tile, 8 waves, BK=64, 4-phase --------
// R3 post-mortem: 4-phase helped (60->48.5us) but each phase carried TWO
// block barriers + lgkmcnt(0) + sched_barrier(0) — all 8 waves ran the
// read-window and MFMA-window in lockstep, so LDS time and MFMA time ADDED.
// sched_barrier order-pinning is a known regression (m141); explicit
// lgkmcnt(0) before the cluster is worse than the compiler's per-MFMA
// lgkmcnt(4/3/1/0) (m97 asm evidence).
// R4: one barrier per phase (at END). Per phase: {ds_reads || 2 gll16 ->
// setprio(1) MFMA setprio(0) -> s_barrier}. Waves self-stagger: one wave's
// MFMA overlaps another's ds_reads (also gives setprio its role diversity).
// Data-deps generate precise lgkmcnt. Barriers are asm("s_barrier","memory")
// = compiler ordering fence without counter drain.
//
// Residency/WAR invariants (unchanged from R3):
//  - stage cadence: ph0/ph1 -> B(u+1), ph2 -> A(u+1) rows 64-127/192-255
//    (free slot), ph3 -> A(u+2) rows 0-63/128-191 into CURRENT slot (their
//    last reads are ph2's, ordered by ph2-end barrier).
//  - tile-end: outstanding = 2 oldest (prev ph3) + 8 (this tile);
//    vmcnt(2) drains exactly tile u+1's 8 loads, leaves u+2's A-X in flight.
//
// LDS swizzle: row of 8 16B-chunks, chunk col c stored at c ^ ((row>>1)&7);
// reads de-swizzle with (q or 4+q) ^ ((r16>>1)&7). 2 lanes/bank = free.
__global__ __launch_bounds__(512, 2) void gemm_bt(const __bf16* __restrict__ A,
                                                  const __bf16* __restrict__ B,
                                                  __bf16* __restrict__ Cp) {
    __shared__ __attribute__((aligned(16))) __bf16 As[2 * ATILE];
    __shared__ __attribute__((aligned(16))) __bf16 Bs[2 * ATILE];

    const int tid  = threadIdx.x;
    const int wave = tid >> 6, lane = tid & 63;
    const int q    = lane >> 4, r16 = lane & 15;
    const int m0 = blockIdx.x * 256, n0 = blockIdx.y * 256, k0 = blockIdx.z * KS;
    const int wm = wave >> 2, wn = wave & 3;     // 2x4 waves; per-wave 128x64 out

    // staging: per matrix, tile = 2048 chunks of 16B; chunk g: row=g>>3, pos=g&7,
    // source col c = pos ^ ((row>>1)&7). Thread t covers chunks t, 512+t,
    // 1024+t, 1536+t (row groups 0/64/128/192; same c since offsets = 0 mod 8).
    const int sr = tid >> 3;                           // 0..63
    const int sc = (tid & 7) ^ ((tid >> 4) & 7);       // de-swizzled source col
    const __bf16* gA0 = A + (size_t)(m0 + sr) * KT       + k0 + sc * 8; // rows   0- 63
    const __bf16* gA1 = A + (size_t)(m0 + 64  + sr) * KT + k0 + sc * 8; // rows  64-127
    const __bf16* gA2 = A + (size_t)(m0 + 128 + sr) * KT + k0 + sc * 8; // rows 128-191
    const __bf16* gA3 = A + (size_t)(m0 + 192 + sr) * KT + k0 + sc * 8; // rows 192-255
    const __bf16* gB0 = B + (size_t)(n0 + sr) * KT       + k0 + sc * 8;
    const __bf16* gB1 = B + (size_t)(n0 + 64  + sr) * KT + k0 + sc * 8;
    const __bf16* gB2 = B + (size_t)(n0 + 128 + sr) * KT + k0 + sc * 8;
    const __bf16* gB3 = B + (size_t)(n0 + 192 + sr) * KT + k0 + sc * 8;

    f32x4 acc[8][4] = {};

    // read offsets (elements). swl = (row>>1)&7 reduces to (r16>>1)&7 for all
    // row bases used (wm*128, wn*64, mi*16, ni*16 are all 0 mod 16).
    const int swl = (r16 >> 1) & 7;
    const int qx0 = ((q)     ^ swl) * 8;         // ks=0 chunk
    const int qx1 = ((4 + q) ^ swl) * 8;         // ks=1 chunk
    const int aro = (wm * 128 + r16) * 64;
    const int bro = (wn * 64  + r16) * 64;

    // prologue: tile 0 full (8 loads) + tile 1's A-X rows (2 loads) in order.
    gll16(gA0, &As[(size_t)tid * 8]);
    gll16(gA1, &As[(size_t)(512 + tid) * 8]);
    gll16(gA2, &As[(size_t)(1024 + tid) * 8]);
    gll16(gA3, &As[(size_t)(1536 + tid) * 8]);
    gll16(gB0, &Bs[(size_t)tid * 8]);
    gll16(gB1, &Bs[(size_t)(512 + tid) * 8]);
    gll16(gB2, &Bs[(size_t)(1024 + tid) * 8]);
    gll16(gB3, &Bs[(size_t)(1536 + tid) * 8]);
    gll16(gA0 + 64, &As[(size_t)(ATILE + tid * 8)]);
    gll16(gA2 + 64, &As[(size_t)(ATILE + (1024 + tid) * 8)]);
    asm volatile("s_waitcnt vmcnt(2)" ::: "memory");   // tile 0 resident
    asm volatile("s_barrier" ::: "memory");

    bf16x8 a[4], b[4];
    for (int u = 0; u < NT2; ++u) {
        const int s   = u & 1;
        const int cbo = s * ATILE;               // compute slot (tile u)
        const int so1 = (s ^ 1) * ATILE;         // slot for tile u+1
        const int k1  = (u + 1) * 64;
        const int k2  = (u + 2) * 64;
        // Tail (u+1/u+2 >= NT2): sources read <=256 B past A/B row ends but
        // stay inside mapped ws (spill into next ws region); never consumed.

        // -------- phase 0: ks=0, mi 0..3 (8 ds_read) --------
#pragma unroll
        for (int mi = 0; mi < 4; ++mi) a[mi] = *(const bf16x8*)(As + cbo + aro + mi * 1024 + qx0);
#pragma unroll
        for (int ni = 0; ni < 4; ++ni) b[ni] = *(const bf16x8*)(Bs + cbo + bro + ni * 1024 + qx0);
        gll16(gB0 + k1, &Bs[(size_t)(so1 + tid * 8)]);
        gll16(gB1 + k1, &Bs[(size_t)(so1 + (512 + tid) * 8)]);
        __builtin_amdgcn_s_setprio(1);
#pragma unroll
        for (int mi = 0; mi < 4; ++mi)
#pragma unroll
            for (int ni = 0; ni < 4; ++ni)
                acc[mi][ni] = __builtin_amdgcn_mfma_f32_16x16x32_bf16(a[mi], b[ni], acc[mi][ni], 0, 0, 0);
        __builtin_amdgcn_s_setprio(0);
        asm volatile("s_barrier" ::: "memory");

        // -------- phase 1: ks=0, mi 4..7 (4 ds_read, reuse b) --------
#pragma unroll
        for (int mi = 0; mi < 4; ++mi) a[mi] = *(const bf16x8*)(As + cbo + aro + (4 + mi) * 1024 + qx0);
        gll16(gB2 + k1, &Bs[(size_t)(so1 + (1024 + tid) * 8)]);
        gll16(gB3 + k1, &Bs[(size_t)(so1 + (1536 + tid) * 8)]);
        __builtin_amdgcn_s_setprio(1);
#pragma unroll
        for (int mi = 0; mi < 4; ++mi)
#pragma unroll
            for (int ni = 0; ni < 4; ++ni)
                acc[4 + mi][ni] = __builtin_amdgcn_mfma_f32_16x16x32_bf16(a[mi], b[ni], acc[4 + mi][ni], 0, 0, 0);
        __builtin_amdgcn_s_setprio(0);
        asm volatile("s_barrier" ::: "memory");

        // -------- phase 2: ks=1, mi 0..3 (8 ds_read) --------
#pragma unroll
        for (int mi = 0; mi < 4; ++mi) a[mi] = *(const bf16x8*)(As + cbo + aro + mi * 1024 + qx1);
#pragma unroll
        for (int ni = 0; ni < 4; ++ni) b[ni] = *(const bf16x8*)(Bs + cbo + bro + ni * 1024 + qx1);
        gll16(gA1 + k1, &As[(size_t)(so1 + (512 + tid) * 8)]);
        gll16(gA3 + k1, &As[(size_t)(so1 + (1536 + tid) * 8)]);
        __builtin_amdgcn_s_setprio(1);
#pragma unroll
        for (int mi = 0; mi < 4; ++mi)
#pragma unroll
            for (int ni = 0; ni < 4; ++ni)
                acc[mi][ni] = __builtin_amdgcn_mfma_f32_16x16x32_bf16(a[mi], b[ni], acc[mi][ni], 0, 0, 0);
        __builtin_amdgcn_s_setprio(0);
        // ph2-end barrier orders all waves' ks=1 A-row reads BEFORE ph3's
        // in-slot stage issue (WAR safety for the u+2 prefetch).
        asm volatile("s_barrier" ::: "memory");

        // -------- phase 3: ks=1, mi 4..7 (4 ds_read, reuse b) --------
#pragma unroll
        for (int mi = 0; mi < 4; ++mi) a[mi] = *(const bf16x8*)(As + cbo + aro + (4 + mi) * 1024 + qx1);
        gll16(gA0 + k2, &As[(size_t)(cbo + tid * 8)]);
        gll16(gA2 + k2, &As[(size_t)(cbo + (1024 + tid) * 8)]);
        __builtin_amdgcn_s_setprio(1);
#pragma unroll
        for (int mi = 0; mi < 4; ++mi)
#pragma unroll
            for (int ni = 0; ni < 4; ++ni)
                acc[4 + mi][ni] = __builtin_amdgcn_mfma_f32_16x16x32_bf16(a[mi], b[ni], acc[4 + mi][ni], 0, 0, 0);
        __builtin_amdgcn_s_setprio(0);
        // counted per-tile wait: outstanding = 2 oldest (prev ph3) + 8 (this
        // tile); drain to 2 -> tile u+1 fully resident, u+2's A-X in flight.
        asm volatile("s_waitcnt vmcnt(2)" ::: "memory");
        asm volatile("s_barrier" ::: "memory");
    }

    // epilogue: C/D layout col=lane&15, row=(lane>>4)*4+reg; bf16 partials
    __bf16* Cb = Cp + (size_t)blockIdx.z * CPE;
#pragma unroll
    for (int mi = 0; mi < 8; ++mi) {
        const int row = m0 + wm * 128 + mi * 16 + q * 4;
#pragma unroll
        for (int ni = 0; ni < 4; ++ni) {
            const int col = n0 + wn * 64 + ni * 16 + r16;
#pragma unroll
            for (int r = 0; r < 4; ++r)
                Cb[(size_t)(row + r) * 512 + col] = (__bf16)acc[mi][ni][r];
        }
    }
}

// ---- kernel 3: sum 8 bf16 partials + LayerNorm, one wave per row ----------
__global__ void ln_kernel(const __bf16* __restrict__ Cp, const float* __restrict__ gamma,
                          const float* __restrict__ beta, float* __restrict__ out) {
    const int tid  = threadIdx.x;
    const int wave = tid >> 6, lane = tid & 63;
    const int row  = blockIdx.x * 4 + wave;
    const size_t base = (size_t)row * 512 + lane * 8;   // 8 contiguous cols/lane

    float v[8] = {};
    float s = 0.f, s2 = 0.f;
#pragma unroll
    for (int z = 0; z < SPLITS; ++z) {
        bf16x8 p = *(const bf16x8*)(Cp + (size_t)z * CPE + base);
#pragma unroll
        for (int j = 0; j < 8; ++j) v[j] += (float)p[j];
    }
#pragma unroll
    for (int j = 0; j < 8; ++j) { s += v[j]; s2 += v[j] * v[j]; }
#pragma unroll
    for (int m = 32; m >= 1; m >>= 1) {
        s  += __shfl_xor(s, m);
        s2 += __shfl_xor(s2, m);
    }
    const float mean = s * (1.0f / 512.0f);
    const float var  = s2 * (1.0f / 512.0f) - mean * mean;
    const float rs   = rsqrtf(var + 1e-5f);
    float4 o0, o1;
    const float4 g0 = *(const float4*)&gamma[lane * 8];
    const float4 g1 = *(const float4*)&gamma[lane * 8 + 4];
    const float4 b0 = *(const float4*)&beta[lane * 8];
    const float4 b1 = *(const float4*)&beta[lane * 8 + 4];
    o0.x = (v[0] - mean) * rs * g0.x + b0.x;
    o0.y = (v[1] - mean) * rs * g0.y + b0.y;
    o0.z = (v[2] - mean) * rs * g0.z + b0.z;
    o0.w = (v[3] - mean) * rs * g0.w + b0.w;
    o1.x = (v[4] - mean) * rs * g1.x + b1.x;
    o1.y = (v[5] - mean) * rs * g1.y + b1.y;
    o1.z = (v[6] - mean) * rs * g1.z + b1.z;
    o1.w = (v[7] - mean) * rs * g1.w + b1.w;
    *(float4*)&out[base]     = o0;
    *(float4*)&out[base + 4] = o1;
}

extern "C" void kernel_launch(void* const* d_in, const int* in_sizes, int n_in,
                              void* d_out, int out_size, void* d_ws, size_t ws_size,
                              hipStream_t stream) {
    const float* x     = (const float*)d_in[0];
    const float* W     = (const float*)d_in[1];
    const float* Wb    = (const float*)d_in[2];
    const float* gamma = (const float*)d_in[3];
    const float* beta  = (const float*)d_in[4];
    float* out = (float*)d_out;

    char* ws = (char*)d_ws;
    __bf16* A  = (__bf16*)ws;                        // 71,303,168 B
    __bf16* Bm = (__bf16*)(ws + 71303168);           //  8,912,896 B
    __bf16* Cp = (__bf16*)(ws + 80216064);           // 33,554,432 B

    prep_AB<<<8192 + 4352, 256, 0, stream>>>(x, W, Wb, A, Bm);
    dim3 g(16, 2, SPLITS);
    gemm_bt<<<g, 512, 0, stream>>>(A, Bm, Cp);
    ln_kernel<<<1024, 256, 0, stream>>>(Cp, gamma, beta, out);
}

// Round 7
// 133.508 us; speedup vs baseline: 1.1403x; 1.0231x over previous
//
#include <hip/hip_runtime.h>
#include <hip/hip_bf16.h>

// KAN layer: out = einsum('bik,jik->bj', rbf(x), W) + silu(x)@Wb^T, then LN.
// GEMM view: C[4096,512] = A[4096,8704] * B[512,8704]^T in bf16 MFMA, where
// A = [rbf basis(x) | silu(x)]. A is NOT materialized: the basis part
// (k<8192) is computed inside the GEMM from x (16 bf16 per x float); only
// the small silu part (4096x512 bf16 = 4.2 MB) is pre-materialized. Kills
// prep's 71.3 MB A-write and the gemm's 71 MB A-fetch.
//
// R5/R6 post-mortem: identical absmax (7.515625) under two different sync
// regimes => deterministic data bug, not ordering. Found it: B staging used
// the GLOBAL kn (= k0 + (u+1)*64) as an offset on gB* pointers that ALREADY
// include k0 — double-counted k0, wrong B tiles for all z>=1 (z=0 correct,
// hence partial error). Global kn is only for x-cols / basis-silu switch /
// Asilu cols (those bases have no k0). R7: tile-local k1 for B, kn for the
// rest. Sync stays R6's compiler-understood form.
//
// d_ws layout (uses 46.7 MB of the 113.7 MB ws):
//   Asilu bf16 [4096][512]   @ 0          ( 4,194,304 B)  silu(x)
//   Bm    bf16 [512][8704]   @ 4194304    ( 8,912,896 B)  Bm = [W | Wb]
//   Cp    bf16 [8][4096][512]@ 13107200   (33,554,432 B)  split-K partials

typedef __bf16 bf16x8 __attribute__((ext_vector_type(8)));
typedef __bf16 bf16x4 __attribute__((ext_vector_type(4)));
typedef float  f32x4  __attribute__((ext_vector_type(4)));

#define KT 8704            // total K = 512*16 + 512
#define SPLITS 8
#define KS (KT / SPLITS)   // 1088 per z-block
#define NT2 (KS / 64)      // 17 K-tiles of BK=64
#define CPE (4096 * 512)   // elements per partial
#define ATILE (256 * 64)   // one tile slot per matrix: 256 rows x 64 k, elems

__device__ __forceinline__ void gll16(const __bf16* g, __bf16* l) {
    __builtin_amdgcn_global_load_lds(
        (const __attribute__((address_space(1))) void*)g,
        (__attribute__((address_space(3))) void*)l, 16, 0, 0);
}

// ---- kernel 1: Asilu = silu(x) (bf16), Bm = [W | Wb] (bf16) ---------------
__global__ void prep_AB(const float* __restrict__ x, const float* __restrict__ W,
                        const float* __restrict__ Wb, __bf16* __restrict__ Asilu,
                        __bf16* __restrict__ B) {
    if (blockIdx.x < 1024) {                     // silu: 8 elems/thread
        int t = blockIdx.x * 256 + threadIdx.x;  // 0 .. 262143
        int e = t * 8;
        float4 v0 = *(const float4*)&x[e];
        float4 v1 = *(const float4*)&x[e + 4];
        float vs[8] = {v0.x, v0.y, v0.z, v0.w, v1.x, v1.y, v1.z, v1.w};
        bf16x8 o;
#pragma unroll
        for (int j = 0; j < 8; ++j) o[j] = (__bf16)(vs[j] / (1.0f + __expf(-vs[j])));
        *(bf16x8*)&Asilu[e] = o;
    } else {                                     // B-part: cast W|Wb, 4 elems/thread
        int t = (blockIdx.x - 1024) * 256 + threadIdx.x;  // 0 .. 512*2176
        int j = t / 2176;
        int c = (t - j * 2176) * 4;
        float4 v;
        if (c < 8192) v = *(const float4*)&W[(size_t)j * 8192 + c];
        else          v = *(const float4*)&Wb[(size_t)j * 512 + (c - 8192)];
        bf16x4 o;
        o[0] = (__bf16)v.x; o[1] = (__bf16)v.y; o[2] = (__bf16)v.z; o[3] = (__bf16)v.w;
        *(bf16x4*)&B[(size_t)j * KT + c] = o;
    }
}

// ---- kernel 2: fused split-K GEMM, 256x256 tile, 8 waves, BK=64, 4-phase --
// Per K-tile: ph0 {ds_read a0-3,b; 2 gll16 B(u+1); x-load} -> bar ->
//             ph1 {a4-7; 2 gll16 B(u+1); silu gll16 if !nb} -> bar ->
//             ph2 {a0-3,b ks1; silu gll16 if !nb} -> bar ->
//             ph3 {a4-7 ks1; basis exp+ds_write if nb} -> __syncthreads().
// Each phase: setprio(1) around its 16 MFMA. All staging targets slot^1;
// slot^1 was last read at tile u-1 (drained by u-1's __syncthreads) ->
// WAR-safe. __syncthreads() at tile end publishes ds_writes AND drains the
// B/silu DMA before the slot swap.
//
// LDS chunk layout: per tile slot, row r has 8 chunks of 16B (BK=64 bf16);
// source chunk c stored at position c ^ ((r>>1)&7); reads de-swizzle with
// (q or 4+q) ^ ((r16>>1)&7). 2 lanes/bank on reads = free.
__global__ __launch_bounds__(512, 2) void gemm_bt(const float* __restrict__ xg,
                                                  const __bf16* __restrict__ Sg,
                                                  const __bf16* __restrict__ B,
                                                  __bf16* __restrict__ Cp) {
    __shared__ __attribute__((aligned(16))) __bf16 As[2 * ATILE];
    __shared__ __attribute__((aligned(16))) __bf16 Bs[2 * ATILE];

    const int tid  = threadIdx.x;
    const int wave = tid >> 6, lane = tid & 63;
    const int q    = lane >> 4, r16 = lane & 15;
    const int m0 = blockIdx.x * 256, n0 = blockIdx.y * 256, k0 = blockIdx.z * KS;
    const int wm = wave >> 2, wn = wave & 3;     // 2x4 waves; per-wave 128x64 out

    // gll16 staging map (B and silu-A): chunk g: row=g>>3, pos=g&7, source
    // col c = pos ^ ((row>>1)&7). Thread t covers chunks t,512+t,1024+t,1536+t.
    const int sr = tid >> 3;                           // 0..63
    const int sc = (tid & 7) ^ ((tid >> 4) & 7);       // de-swizzled source col
    const __bf16* gB0 = B + (size_t)(n0 + sr) * KT       + k0 + sc * 8;
    const __bf16* gB1 = B + (size_t)(n0 + 64  + sr) * KT + k0 + sc * 8;
    const __bf16* gB2 = B + (size_t)(n0 + 128 + sr) * KT + k0 + sc * 8;
    const __bf16* gB3 = B + (size_t)(n0 + 192 + sr) * KT + k0 + sc * 8;
    // silu source (row stride 512; per-tile kk offset added later; NO k0)
    const __bf16* gS0 = Sg + (size_t)(m0 + sr) * 512       + sc * 8;
    const __bf16* gS1 = Sg + (size_t)(m0 + 64  + sr) * 512 + sc * 8;
    const __bf16* gS2 = Sg + (size_t)(m0 + 128 + sr) * 512 + sc * 8;
    const __bf16* gS3 = Sg + (size_t)(m0 + 192 + sr) * 512 + sc * 8;

    // basis staging map: thread t owns row pr = t>>1, x-col pair pha = t&1
    // (cols 2*pha, 2*pha+1 of the tile's 4 x-cols).
    const int pr   = tid >> 1, pha = tid & 1;
    const int swzr = (pr >> 1) & 7;
    const int wb0  = pr * 64;                          // row base, elems
    const float* xrow = xg + (size_t)(m0 + pr) * 512 + 2 * pha;  // NO k0

    f32x4 acc[8][4] = {};

    // read offsets: swl=(row>>1)&7 reduces to (r16>>1)&7 (all row bases 0 mod 16)
    const int swl = (r16 >> 1) & 7;
    const int qx0 = ((q)     ^ swl) * 8;         // ks=0 chunk
    const int qx1 = ((4 + q) ^ swl) * 8;         // ks=1 chunk
    const int aro = (wm * 128 + r16) * 64;
    const int bro = (wn * 64  + r16) * 64;

    // compute basis for one float2 of x and ds_write 4 swizzled chunks
    auto write_basis = [&](float2 xv, int so) {
#pragma unroll
        for (int e = 0; e < 2; ++e) {
            const float xc = e ? xv.y : xv.x;
            const float zb = 3.75f * xc + 7.5f;  // z_j = zb - j
            const int   ci = 2 * pha + e;
            bf16x8 lo, hi;
#pragma unroll
            for (int j = 0; j < 8; ++j)  { float z = zb - (float)j;       lo[j]     = (__bf16)__expf(-z * z); }
#pragma unroll
            for (int j = 8; j < 16; ++j) { float z = zb - (float)j;       hi[j - 8] = (__bf16)__expf(-z * z); }
            *(bf16x8*)(As + so + wb0 + ((2 * ci)     ^ swzr) * 8) = lo;
            *(bf16x8*)(As + so + wb0 + ((2 * ci + 1) ^ swzr) * 8) = hi;
        }
    };

    // prologue: B(0) via gll16 (gB* already at k0); A(0) basis (tile 0 is
    // basis for all z: max k0 = 7616 < 8192) computed from x into slot 0.
    float2 xv0 = *(const float2*)(xrow + (k0 >> 4));
    gll16(gB0, &Bs[(size_t)tid * 8]);
    gll16(gB1, &Bs[(size_t)(512 + tid) * 8]);
    gll16(gB2, &Bs[(size_t)(1024 + tid) * 8]);
    gll16(gB3, &Bs[(size_t)(1536 + tid) * 8]);
    write_basis(xv0, 0);
    __syncthreads();

    bf16x8 a[4], b[4];
    float2 xn = xv0;                             // next-tile x (basis path)
    for (int u = 0; u < NT2; ++u) {
        const int s   = u & 1;
        const int cbo = s * ATILE;               // compute slot (tile u)
        const int so1 = (s ^ 1) * ATILE;         // staging slot (tile u+1)
        const int k1  = (u + 1) * 64;            // tile-local offset (for gB*: k0 already baked in)
        const int kn  = k0 + k1;                 // GLOBAL k-base of tile u+1 (for x / nb / kk)
        const bool nb = kn < 8192;               // next tile is basis?
        const int kk  = kn - 8192;               // silu col base (when !nb)
        // Tail (u+1==NT2): basis z<7 reads valid x cols (<=479); silu z=7
        // reads <=512 elems past Asilu rows -> lands in Bm (mapped, unused);
        // B reads <=112 B past Bm -> lands in Cp (mapped, unused).

        // -------- phase 0: ks=0, mi 0..3 (8 ds_read) --------
#pragma unroll
        for (int mi = 0; mi < 4; ++mi) a[mi] = *(const bf16x8*)(As + cbo + aro + mi * 1024 + qx0);
#pragma unroll
        for (int ni = 0; ni < 4; ++ni) b[ni] = *(const bf16x8*)(Bs + cbo + bro + ni * 1024 + qx0);
        gll16(gB0 + k1, &Bs[(size_t)(so1 + tid * 8)]);
        gll16(gB1 + k1, &Bs[(size_t)(so1 + (512 + tid) * 8)]);
        if (nb) xn = *(const float2*)(xrow + (kn >> 4));
        __builtin_amdgcn_s_setprio(1);
#pragma unroll
        for (int mi = 0; mi < 4; ++mi)
#pragma unroll
            for (int ni = 0; ni < 4; ++ni)
                acc[mi][ni] = __builtin_amdgcn_mfma_f32_16x16x32_bf16(a[mi], b[ni], acc[mi][ni], 0, 0, 0);
        __builtin_amdgcn_s_setprio(0);
        __builtin_amdgcn_s_barrier();

        // -------- phase 1: ks=0, mi 4..7 (4 ds_read, reuse b) --------
#pragma unroll
        for (int mi = 0; mi < 4; ++mi) a[mi] = *(const bf16x8*)(As + cbo + aro + (4 + mi) * 1024 + qx0);
        gll16(gB2 + k1, &Bs[(size_t)(so1 + (1024 + tid) * 8)]);
        gll16(gB3 + k1, &Bs[(size_t)(so1 + (1536 + tid) * 8)]);
        if (!nb) {
            gll16(gS0 + kk, &As[(size_t)(so1 + tid * 8)]);
            gll16(gS1 + kk, &As[(size_t)(so1 + (512 + tid) * 8)]);
        }
        __builtin_amdgcn_s_setprio(1);
#pragma unroll
        for (int mi = 0; mi < 4; ++mi)
#pragma unroll
            for (int ni = 0; ni < 4; ++ni)
                acc[4 + mi][ni] = __builtin_amdgcn_mfma_f32_16x16x32_bf16(a[mi], b[ni], acc[4 + mi][ni], 0, 0, 0);
        __builtin_amdgcn_s_setprio(0);
        __builtin_amdgcn_s_barrier();

        // -------- phase 2: ks=1, mi 0..3 (8 ds_read) --------
#pragma unroll
        for (int mi = 0; mi < 4; ++mi) a[mi] = *(const bf16x8*)(As + cbo + aro + mi * 1024 + qx1);
#pragma unroll
        for (int ni = 0; ni < 4; ++ni) b[ni] = *(const bf16x8*)(Bs + cbo + bro + ni * 1024 + qx1);
        if (!nb) {
            gll16(gS2 + kk, &As[(size_t)(so1 + (1024 + tid) * 8)]);
            gll16(gS3 + kk, &As[(size_t)(so1 + (1536 + tid) * 8)]);
        }
        __builtin_amdgcn_s_setprio(1);
#pragma unroll
        for (int mi = 0; mi < 4; ++mi)
#pragma unroll
            for (int ni = 0; ni < 4; ++ni)
                acc[mi][ni] = __builtin_amdgcn_mfma_f32_16x16x32_bf16(a[mi], b[ni], acc[mi][ni], 0, 0, 0);
        __builtin_amdgcn_s_setprio(0);
        __builtin_amdgcn_s_barrier();

        // -------- phase 3: ks=1, mi 4..7 (4 ds_read, reuse b) --------
        // basis: exp + 4 ds_write_b128 into slot^1 (last read at tile u-1,
        // drained by u-1's __syncthreads; published by this tile's
        // __syncthreads before tile u+1's ph0 reads).
#pragma unroll
        for (int mi = 0; mi < 4; ++mi) a[mi] = *(const bf16x8*)(As + cbo + aro + (4 + mi) * 1024 + qx1);
        if (nb) write_basis(xn, so1);
        __builtin_amdgcn_s_setprio(1);
#pragma unroll
        for (int mi = 0; mi < 4; ++mi)
#pragma unroll
            for (int ni = 0; ni < 4; ++ni)
                acc[4 + mi][ni] = __builtin_amdgcn_mfma_f32_16x16x32_bf16(a[mi], b[ni], acc[4 + mi][ni], 0, 0, 0);
        __builtin_amdgcn_s_setprio(0);
        // tile end: compiler-understood full drain + barrier. Publishes the
        // basis ds_writes and drains the B/silu DMA (issued 1-3 phases ago).
        __syncthreads();
    }

    // epilogue: C/D layout col=lane&15, row=(lane>>4)*4+reg; bf16 partials
    __bf16* Cb = Cp + (size_t)blockIdx.z * CPE;
#pragma unroll
    for (int mi = 0; mi < 8; ++mi) {
        const int row = m0 + wm * 128 + mi * 16 + q * 4;
#pragma unroll
        for (int ni = 0; ni < 4; ++ni) {
            const int col = n0 + wn * 64 + ni * 16 + r16;
#pragma unroll
            for (int r = 0; r < 4; ++r)
                Cb[(size_t)(row + r) * 512 + col] = (__bf16)acc[mi][ni][r];
        }
    }
}

// ---- kernel 3: sum 8 bf16 partials + LayerNorm, one wave per row ----------
__global__ void ln_kernel(const __bf16* __restrict__ Cp, const float* __restrict__ gamma,
                          const float* __restrict__ beta, float* __restrict__ out) {
    const int tid  = threadIdx.x;
    const int wave = tid >> 6, lane = tid & 63;
    const int row  = blockIdx.x * 4 + wave;
    const size_t base = (size_t)row * 512 + lane * 8;   // 8 contiguous cols/lane

    float v[8] = {};
    float s = 0.f, s2 = 0.f;
#pragma unroll
    for (int z = 0; z < SPLITS; ++z) {
        bf16x8 p = *(const bf16x8*)(Cp + (size_t)z * CPE + base);
#pragma unroll
        for (int j = 0; j < 8; ++j) v[j] += (float)p[j];
    }
#pragma unroll
    for (int j = 0; j < 8; ++j) { s += v[j]; s2 += v[j] * v[j]; }
#pragma unroll
    for (int m = 32; m >= 1; m >>= 1) {
        s  += __shfl_xor(s, m);
        s2 += __shfl_xor(s2, m);
    }
    const float mean = s * (1.0f / 512.0f);
    const float var  = s2 * (1.0f / 512.0f) - mean * mean;
    const float rs   = rsqrtf(var + 1e-5f);
    float4 o0, o1;
    const float4 g0 = *(const float4*)&gamma[lane * 8];
    const float4 g1 = *(const float4*)&gamma[lane * 8 + 4];
    const float4 b0 = *(const float4*)&beta[lane * 8];
    const float4 b1 = *(const float4*)&beta[lane * 8 + 4];
    o0.x = (v[0] - mean) * rs * g0.x + b0.x;
    o0.y = (v[1] - mean) * rs * g0.y + b0.y;
    o0.z = (v[2] - mean) * rs * g0.z + b0.z;
    o0.w = (v[3] - mean) * rs * g0.w + b0.w;
    o1.x = (v[4] - mean) * rs * g1.x + b1.x;
    o1.y = (v[5] - mean) * rs * g1.y + b1.y;
    o1.z = (v[6] - mean) * rs * g1.z + b1.z;
    o1.w = (v[7] - mean) * rs * g1.w + b1.w;
    *(float4*)&out[base]     = o0;
    *(float4*)&out[base + 4] = o1;
}

extern "C" void kernel_launch(void* const* d_in, const int* in_sizes, int n_in,
                              void* d_out, int out_size, void* d_ws, size_t ws_size,
                              hipStream_t stream) {
    const float* x     = (const float*)d_in[0];
    const float* W     = (const float*)d_in[1];
    const float* Wb    = (const float*)d_in[2];
    const float* gamma = (const float*)d_in[3];
    const float* beta  = (const float*)d_in[4];
    float* out = (float*)d_out;

    char* ws = (char*)d_ws;
    __bf16* Asilu = (__bf16*)ws;                     //  4,194,304 B
    __bf16* Bm    = (__bf16*)(ws + 4194304);         //  8,912,896 B
    __bf16* Cp    = (__bf16*)(ws + 13107200);        // 33,554,432 B

    prep_AB<<<1024 + 4352, 256, 0, stream>>>(x, W, Wb, Asilu, Bm);
    dim3 g(16, 2, SPLITS);
    gemm_bt<<<g, 512, 0, stream>>>(x, Asilu, Bm, Cp);
    ln_kernel<<<1024, 256, 0, stream>>>(Cp, gamma, beta, out);
}